// Round 1
// baseline (381.417 us; speedup 1.0000x reference)
//
#include <hip/hip_runtime.h>
#include <math.h>

#define CLASSES 8
#define SIZE 512
#define ISZ 512      // INPUT_SIZE
#define CSZ 512      // CONTEXT_SIZE
#define BATCH 64
#define CMS 4
#define NBUCKET 16
#define LR 0.01f
#define WCLIP 5.0f
// LDS row stride (floats) for W slice: 516 -> gather banks 4*(idx+d4)%32,
// only idx vs idx+8 alias (2-way broadcast-free on CDNA4).
#define WSTRIDE 516

__global__ __launch_bounds__(256) void transpose_logits(
    const float* __restrict__ L,   // (C, I, B)
    float* __restrict__ Lt)        // (C, B, I)
{
    int o = blockIdx.x * 256 + threadIdx.x;    // over C*B*I = 262144
    int i = o & (ISZ - 1);
    int b = (o >> 9) & (BATCH - 1);
    int c = o >> 15;
    Lt[o] = L[(c * ISZ + i) * BATCH + b];
}

__global__ __launch_bounds__(256) void gln_fused(
    const float* __restrict__ logits,   // (C, I, B)
    const float* __restrict__ context,  // (B, D)
    const float* __restrict__ target,   // (C, B)
    const float* __restrict__ cmaps,    // (C, S, K, D)
    const float* __restrict__ cbias,    // (C, S, K, 1)
    const float* __restrict__ weights,  // (C, S, 16, I)
    const float* __restrict__ Lt,       // (C, B, I)
    float* __restrict__ out,            // (C, S, B)
    float* __restrict__ outW)           // (C, S, 16, I)
{
    __shared__ float Wl[NBUCKET * WSTRIDE];   // 33 KB, padded rows
    __shared__ int   bits[CMS * BATCH];
    __shared__ float partial[4 * BATCH];
    __shared__ int   idx_l[BATCH];
    __shared__ int   blast[NBUCKET];
    __shared__ float diff_l[BATCH];

    const int tid  = threadIdx.x;
    const int cs   = blockIdx.x;       // c*SIZE + s
    const int c    = cs >> 9;
    const int lane = tid & 63;
    const int wv   = tid >> 6;         // wave id 0..3

    // ---- Stage W slice (16 x 512 f32) into padded LDS, coalesced ----
    const float* gW = weights + (size_t)cs * (NBUCKET * ISZ);
    #pragma unroll
    for (int it = 0; it < 8; ++it) {
        int f    = tid + it * 256;     // float4 index 0..2047
        int row  = f >> 7;             // 128 float4 per row
        int col4 = f & 127;
        float4 v = reinterpret_cast<const float4*>(gW)[f];
        *reinterpret_cast<float4*>(&Wl[row * WSTRIDE + col4 * 4]) = v;
    }

    // ---- Phase 0: context bits (wave wv handles k = wv) ----
    {
        const int k = wv;
        const float* cm = cmaps + ((size_t)cs * CMS + k) * CSZ;   // wave-uniform row
        const float* cx = context + (size_t)lane * CSZ;           // per-lane row
        float acc = 0.f;
        #pragma unroll 4
        for (int d4 = 0; d4 < CSZ / 4; ++d4) {
            float4 cmv = reinterpret_cast<const float4*>(cm)[d4];
            float4 cxv = reinterpret_cast<const float4*>(cx)[d4];
            acc += cmv.x * cxv.x + cmv.y * cxv.y + cmv.z * cxv.z + cmv.w * cxv.w;
        }
        float bias = cbias[(size_t)cs * CMS + k];
        bits[k * BATCH + lane] = (acc > bias) ? 1 : 0;
    }
    __syncthreads();

    // bucket index for my lane's batch element
    int idx_b = bits[lane] | (bits[BATCH + lane] << 1) |
                (bits[2 * BATCH + lane] << 2) | (bits[3 * BATCH + lane] << 3);
    if (tid < BATCH) idx_l[tid] = idx_b;

    // ---- Phase 2: gather-dot. wave wv covers i in [128*wv, 128*wv+128) ----
    {
        const float* Lc = logits + (size_t)c * ISZ * BATCH;
        float acc = 0.f;
        const int base = idx_b * WSTRIDE + wv * 128;
        const int ib   = wv * 128;
        #pragma unroll 4
        for (int d4 = 0; d4 < 32; ++d4) {
            float4 w4 = *reinterpret_cast<const float4*>(&Wl[base + d4 * 4]);
            int i0 = ib + d4 * 4;
            float l0 = Lc[(i0 + 0) * BATCH + lane];
            float l1 = Lc[(i0 + 1) * BATCH + lane];
            float l2 = Lc[(i0 + 2) * BATCH + lane];
            float l3 = Lc[(i0 + 3) * BATCH + lane];
            acc += w4.x * l0 + w4.y * l1 + w4.z * l2 + w4.w * l3;
        }
        partial[wv * BATCH + lane] = acc;
    }
    __syncthreads();

    // ---- Phase 2b: reduce -> out, diff; scan b_last per bucket ----
    if (tid < BATCH) {
        float s = partial[tid] + partial[BATCH + tid] +
                  partial[2 * BATCH + tid] + partial[3 * BATCH + tid];
        const float lo = -4.595119850134589f;   // logit(0.01)
        const float hi =  4.595119850134589f;
        float oc = fminf(fmaxf(s, lo), hi);
        out[(size_t)cs * BATCH + tid] = oc;
        float sig = 1.f / (1.f + expf(-oc));
        diff_l[tid] = sig - target[c * BATCH + tid];
    } else if (tid >= 64 && tid < 64 + NBUCKET) {
        int j = tid - 64;
        int m = -1;
        for (int b = 0; b < BATCH; ++b) {
            if (idx_l[b] == j) m = b;            // last (max) b wins, np semantics
        }
        blast[j] = m;
    }
    __syncthreads();

    // ---- Phase 3: per-bucket update using b_last only; stream out ----
    float* gO = outW + (size_t)cs * (NBUCKET * ISZ);
    const float* LtC = Lt + (size_t)c * BATCH * ISZ;
    #pragma unroll
    for (int it = 0; it < 8; ++it) {
        int f    = tid + it * 256;
        int row  = f >> 7;
        int col4 = f & 127;
        float4 w4 = *reinterpret_cast<const float4*>(&Wl[row * WSTRIDE + col4 * 4]);
        int bl = blast[row];                      // wave-uniform (row uniform per wave)
        float4 r = w4;
        if (bl >= 0) {
            float coef = LR * diff_l[bl];
            float4 l4  = reinterpret_cast<const float4*>(LtC + (size_t)bl * ISZ)[col4];
            r.x = fminf(fmaxf(w4.x - coef * l4.x, -WCLIP), WCLIP);
            r.y = fminf(fmaxf(w4.y - coef * l4.y, -WCLIP), WCLIP);
            r.z = fminf(fmaxf(w4.z - coef * l4.z, -WCLIP), WCLIP);
            r.w = fminf(fmaxf(w4.w - coef * l4.w, -WCLIP), WCLIP);
        }
        reinterpret_cast<float4*>(gO)[f] = r;
    }
}

extern "C" void kernel_launch(void* const* d_in, const int* in_sizes, int n_in,
                              void* d_out, int out_size, void* d_ws, size_t ws_size,
                              hipStream_t stream) {
    const float* logits  = (const float*)d_in[0];  // (8,512,64)
    const float* context = (const float*)d_in[1];  // (64,512)
    const float* target  = (const float*)d_in[2];  // (8,64)
    const float* cmaps   = (const float*)d_in[3];  // (8,512,4,512)
    const float* cbias   = (const float*)d_in[4];  // (8,512,4,1)
    const float* weights = (const float*)d_in[5];  // (8,512,16,512)

    float* out  = (float*)d_out;                       // (8,512,64)
    float* outW = out + (size_t)CLASSES * SIZE * BATCH; // (8,512,16,512)
    float* Lt   = (float*)d_ws;                        // 1 MB scratch: (8,64,512)

    transpose_logits<<<(CLASSES * BATCH * ISZ) / 256, 256, 0, stream>>>(logits, Lt);
    gln_fused<<<CLASSES * SIZE, 256, 0, stream>>>(
        logits, context, target, cmaps, cbias, weights, Lt, out, outW);
}

// Round 2
// 164.909 us; speedup vs baseline: 2.3129x; 2.3129x over previous
//
#include <hip/hip_runtime.h>
#include <math.h>

#define CLASSES 8
#define SIZE 512
#define ISZ 512
#define CSZ 512
#define BATCH 64
#define CMS 4
#define NBUCKET 16
#define LR 0.01f
#define WCLIP 5.0f
#define WSTRIDE 516   // gather banks 4*(idx+off)%32 -> worst 2-way (free on CDNA4)

// ---------------- pre-pass: packed layouts in d_ws ----------------
// Lt    (B, C*I)      : Lt[b*4096 + ci]                  = logits[ci, b]
// Lpk   (C*I/4, B, 4) : Lpk[(ci>>2)*256 + 4*b + (ci&3)]  = logits[ci, b]
// ctxT4 (D/4, B, 4)   : ctxT4[(d>>2)*256 + 4*b + (d&3)]  = context[b, d]
__global__ __launch_bounds__(256) void pack_pre(
    const float* __restrict__ logits,    // (C*I, B)
    const float* __restrict__ context,   // (B, D)
    float* __restrict__ Lt,
    float* __restrict__ Lpk,
    float* __restrict__ ctxT4)
{
    __shared__ float t[64][65];
    const int bid  = blockIdx.x;
    const int lane = threadIdx.x & 63;
    const int w    = threadIdx.x >> 6;
    if (bid < 64) {
        const int r0 = bid << 6;                     // ci base
        #pragma unroll
        for (int rep = 0; rep < 16; ++rep) {
            int rr = w * 16 + rep;
            t[rr][lane] = logits[(size_t)(r0 + rr) * 64 + lane];
        }
        __syncthreads();
        const int ci = r0 + lane;
        #pragma unroll
        for (int rep = 0; rep < 16; ++rep) {
            int b = w * 16 + rep;
            float v = t[lane][b];
            Lt[(size_t)b * 4096 + ci] = v;
            Lpk[(size_t)(ci >> 2) * 256 + 4 * b + (ci & 3)] = v;
        }
    } else {
        const int c0 = (bid - 64) << 6;              // d base
        #pragma unroll
        for (int rep = 0; rep < 16; ++rep) {
            int rr = w * 16 + rep;                   // b
            t[rr][lane] = context[(size_t)rr * 512 + c0 + lane];
        }
        __syncthreads();
        #pragma unroll
        for (int rep = 0; rep < 16; ++rep) {
            int dd = c0 + w * 16 + rep;              // d
            ctxT4[(size_t)(dd >> 2) * 256 + 4 * lane + (dd & 3)] = t[lane][w * 16 + rep];
        }
    }
}

__global__ __launch_bounds__(256, 4) void gln_fused(
    const float* __restrict__ target,   // (C, B)
    const float* __restrict__ cmaps,    // (C, S, 4, 512)
    const float* __restrict__ cbias,    // (C, S, 4, 1)
    const float* __restrict__ weights,  // (C, S, 16, 512)
    const float* __restrict__ Lt,
    const float* __restrict__ Lpk,
    const float* __restrict__ ctxT4,
    float* __restrict__ out,            // (C, S, B)
    float* __restrict__ outW)           // (C, S, 16, 512)
{
    __shared__ float Wl[NBUCKET * WSTRIDE];   // 33 KB; first 8 KB aliased as cmaps row
    __shared__ int   bits[CMS * BATCH];
    __shared__ float partial[4 * BATCH];
    __shared__ float diff_l[BATCH];
    __shared__ int   blast[NBUCKET];

    const int tid  = threadIdx.x;
    const int cs   = blockIdx.x;       // c*SIZE + s
    const int c    = cs >> 9;
    const int lane = tid & 63;
    const int wv   = tid >> 6;

    // 1) stage cmaps slice (4x512 f32) into Wl[0..2047] (linear, coalesced)
    {
        const float4* gcm = (const float4*)(cmaps + (size_t)cs * (CMS * CSZ));
        float4 a = gcm[tid];
        float4 b = gcm[tid + 256];
        ((float4*)Wl)[tid]       = a;
        ((float4*)Wl)[tid + 256] = b;
    }
    // 2) issue W-slice loads into registers; consumed after phase 0 (latency hidden)
    float4 wreg[8];
    {
        const float4* gW = (const float4*)(weights + (size_t)cs * (NBUCKET * ISZ));
        #pragma unroll
        for (int it = 0; it < 8; ++it) wreg[it] = gW[tid + it * 256];
    }
    __syncthreads();

    // 3) phase 0: distance for k = wv, b = lane (coalesced float4 ctx loads)
    {
        const float4* ct4 = (const float4*)ctxT4 + lane;
        float acc = 0.f;
        #pragma unroll 4
        for (int d4 = 0; d4 < 128; ++d4) {
            float4 cm4 = *(const float4*)&Wl[wv * CSZ + d4 * 4];   // uniform LDS bcast
            float4 cv  = ct4[(size_t)d4 * 64];
            acc += cm4.x * cv.x + cm4.y * cv.y + cm4.z * cv.z + cm4.w * cv.w;
        }
        float bias = cbias[(size_t)cs * CMS + wv];
        bits[wv * BATCH + lane] = (acc > bias) ? 1 : 0;
    }
    __syncthreads();

    // 4) overwrite Wl with weight rows (padded stride); bucket idx per lane
    #pragma unroll
    for (int it = 0; it < 8; ++it) {
        int f = tid + it * 256;
        *(float4*)&Wl[(f >> 7) * WSTRIDE + (f & 127) * 4] = wreg[it];
    }
    int idx_b = bits[lane] | (bits[BATCH + lane] << 1) |
                (bits[2 * BATCH + lane] << 2) | (bits[3 * BATCH + lane] << 3);
    __syncthreads();

    // 5) phase 2: gather-dot; wave wv covers i in [128*wv, 128*wv+128)
    {
        const float4* Lp4 = (const float4*)Lpk;
        const int base4 = (c * 128 + wv * 32) * 64 + lane;
        const int wb    = idx_b * WSTRIDE + wv * 128;
        float acc = 0.f;
        #pragma unroll 4
        for (int d4 = 0; d4 < 32; ++d4) {
            float4 w4 = *(const float4*)&Wl[wb + d4 * 4];
            float4 l4 = Lp4[(size_t)base4 + d4 * 64];
            acc += w4.x * l4.x + w4.y * l4.y + w4.z * l4.z + w4.w * l4.w;
        }
        partial[wv * BATCH + lane] = acc;
    }
    __syncthreads();

    // 6) phase 2b (wave 0 only): out, diff, last-writer per bucket via ballot
    if (wv == 0) {
        float s = partial[lane] + partial[BATCH + lane] +
                  partial[2 * BATCH + lane] + partial[3 * BATCH + lane];
        const float hi = 4.595119850134589f;    // logit(0.99)
        float oc = fminf(fmaxf(s, -hi), hi);
        out[(size_t)cs * BATCH + lane] = oc;
        float sig = 1.f / (1.f + expf(-oc));
        diff_l[lane] = LR * (sig - target[c * BATCH + lane]);
        #pragma unroll
        for (int j = 0; j < NBUCKET; ++j) {
            unsigned long long m = __ballot(idx_b == j);
            if (lane == 0) blast[j] = m ? (63 - __clzll(m)) : -1;   // np last-write-wins
        }
    }
    __syncthreads();

    // 7) phase 3: per-bucket update using b_last only; stream out coalesced
    float* gO = outW + (size_t)cs * (NBUCKET * ISZ);
    const float* LtC = Lt + (size_t)c * ISZ;    // + bl*4096 later
    #pragma unroll
    for (int it = 0; it < 8; ++it) {
        int f    = tid + it * 256;
        int row  = f >> 7;
        int col4 = f & 127;
        float4 w4 = *(const float4*)&Wl[row * WSTRIDE + col4 * 4];
        int bl = blast[row];
        float4 r = w4;
        if (bl >= 0) {
            float coef = diff_l[bl];
            float4 l4  = ((const float4*)(LtC + (size_t)bl * 4096))[col4];
            r.x = fminf(fmaxf(w4.x - coef * l4.x, -WCLIP), WCLIP);
            r.y = fminf(fmaxf(w4.y - coef * l4.y, -WCLIP), WCLIP);
            r.z = fminf(fmaxf(w4.z - coef * l4.z, -WCLIP), WCLIP);
            r.w = fminf(fmaxf(w4.w - coef * l4.w, -WCLIP), WCLIP);
        }
        ((float4*)gO)[f] = r;
    }
}

extern "C" void kernel_launch(void* const* d_in, const int* in_sizes, int n_in,
                              void* d_out, int out_size, void* d_ws, size_t ws_size,
                              hipStream_t stream) {
    const float* logits  = (const float*)d_in[0];  // (8,512,64)
    const float* context = (const float*)d_in[1];  // (64,512)
    const float* target  = (const float*)d_in[2];  // (8,64)
    const float* cmaps   = (const float*)d_in[3];  // (8,512,4,512)
    const float* cbias   = (const float*)d_in[4];  // (8,512,4,1)
    const float* weights = (const float*)d_in[5];  // (8,512,16,512)

    float* out  = (float*)d_out;                        // (8,512,64)
    float* outW = out + (size_t)CLASSES * SIZE * BATCH; // (8,512,16,512)

    float* Lt    = (float*)d_ws;            // 1 MB
    float* Lpk   = Lt + 262144;             // 1 MB
    float* ctxT4 = Lpk + 262144;            // 128 KB

    pack_pre<<<72, 256, 0, stream>>>(logits, context, Lt, Lpk, ctxT4);
    gln_fused<<<CLASSES * SIZE, 256, 0, stream>>>(
        target, cmaps, cbias, weights, Lt, Lpk, ctxT4, out, outW);
}